// Round 9
// baseline (2349.022 us; speedup 1.0000x reference)
//
#include <hip/hip_runtime.h>

typedef __attribute__((ext_vector_type(8))) short short8;
typedef __attribute__((ext_vector_type(4))) float f32x4;

// Problem constants
#define S_LEN 256
#define BATCH 128
#define IN_DIM 1024
#define HID 512
#define G4 2048  // 4*HID

#define SENT 0xFFFFFFFFu  // 2x bf16 NaN; h=o*tanh(c) can never be NaN

// ring: [8 groups][257 slots][16 rows][512 cols] bf16
#define SLOT_U 4096        // uints per slot (16*512/2)
#define SLOT_Q 2048        // qwords per slot
#define GR_U (257 * SLOT_U)

__device__ __forceinline__ unsigned short f32_bf16(float f) {
  unsigned int u = __float_as_uint(f);
  u = (u + 0x7FFFu + ((u >> 16) & 1u)) >> 16;  // RNE
  return (unsigned short)u;
}
__device__ __forceinline__ float bf16_f32(unsigned short h) {
  return __uint_as_float(((unsigned int)h) << 16);
}
__device__ __forceinline__ float sigm(float x) { return 1.0f / (1.0f + __expf(-x)); }
__device__ __forceinline__ float tanh_fast(float x) {
  return 1.0f - 2.0f / (__expf(2.0f * x) + 1.0f);
}

template <bool L2>
__device__ __forceinline__ unsigned long long ld8(const unsigned long long* p) {
  if (L2) return *(volatile const unsigned long long*)p;  // sc0: L1-bypass, L2-served
  return __hip_atomic_load(p, __ATOMIC_RELAXED, __HIP_MEMORY_SCOPE_AGENT);
}
__device__ __forceinline__ unsigned long long ld8_agent(const unsigned long long* p) {
  return __hip_atomic_load(p, __ATOMIC_RELAXED, __HIP_MEMORY_SCOPE_AGENT);
}
template <bool L2>
__device__ __forceinline__ void st4(unsigned* p, unsigned v) {
  if (L2) *(volatile unsigned*)p = v;  // write-through L1 -> shared XCD L2
  else __hip_atomic_store(p, v, __ATOMIC_RELAXED, __HIP_MEMORY_SCOPE_AGENT);
}

// ---------------- conversion kernels ----------------
__global__ void cvt_bf16(const float* __restrict__ src, unsigned short* __restrict__ dst, int n) {
  int i = (blockIdx.x * blockDim.x + threadIdx.x) * 4;
  if (i >= n) return;
  float4 v = *(const float4*)(src + i);
  ushort4 o;
  o.x = f32_bf16(v.x); o.y = f32_bf16(v.y); o.z = f32_bf16(v.z); o.w = f32_bf16(v.w);
  *(ushort4*)(dst + i) = o;
}

// bias fuse + ctrl zero + ring poison: slot0 of each group = 0, slots 1..256 = SENT
__global__ void init_all(const float* __restrict__ b_ih, const float* __restrict__ b_hh,
                         float* __restrict__ bias, unsigned* __restrict__ ctrl,
                         uint4* __restrict__ hring4) {
  int i = blockIdx.x * blockDim.x + threadIdx.x;
  if (i < G4) bias[i] = b_ih[i] + b_hh[i];
  if (i < 64) ctrl[i] = 0u;
  const int SLOT4 = SLOT_U / 4;            // 1024 uint4 per slot
  const int TOT4 = 8 * 257 * SLOT4;        // 2,105,344 uint4
  const uint4 z = make_uint4(0u, 0u, 0u, 0u);
  const uint4 sN = make_uint4(SENT, SENT, SENT, SENT);
  for (int k = i; k < TOT4; k += gridDim.x * blockDim.x) {
    int slot = (k / SLOT4) % 257;
    hring4[k] = (slot == 0) ? z : sN;
  }
}

// ---------------- GEMM: Gx = x_bf16 @ w_ih_bf16^T + bias ----------------
__device__ __forceinline__ void gl_lds16(const void* g, void* l) {
  __builtin_amdgcn_global_load_lds(
      (const __attribute__((address_space(1))) unsigned int*)g,
      (__attribute__((address_space(3))) unsigned int*)l, 16, 0, 0);
}

__global__ __launch_bounds__(256) void gemm_bias(
    const unsigned short* __restrict__ A,   // [32768][1024] bf16
    const unsigned short* __restrict__ Bw,  // [2048][1024] bf16
    const float* __restrict__ bias,         // [2048]
    float* __restrict__ Cout) {             // [32768][2048] fp32
  __shared__ __align__(16) unsigned short As[128 * 32];
  __shared__ __align__(16) unsigned short Bs[128 * 32];
  const int tid = threadIdx.x;
  const int w = tid >> 6, l = tid & 63;
  const int wm = w & 1, wn = w >> 1;
  const int nt = blockIdx.x & 15, mt = blockIdx.x >> 4;

  f32x4 acc[4][4];
#pragma unroll
  for (int i = 0; i < 4; i++)
#pragma unroll
    for (int j = 0; j < 4; j++) acc[i][j] = f32x4{0.f, 0.f, 0.f, 0.f};

  for (int k0 = 0; k0 < 1024; k0 += 32) {
    __syncthreads();
#pragma unroll
    for (int jj = 0; jj < 2; jj++) {
      int cid = (w * 2 + jj) * 64 + l;
      int row = cid >> 2, kc = cid & 3;
      const unsigned short* ga = A + (size_t)(mt * 128 + row) * 1024 + k0 + kc * 8;
      gl_lds16(ga, As + (w * 2 + jj) * 512);
      const unsigned short* gb = Bw + (size_t)(nt * 128 + row) * 1024 + k0 + kc * 8;
      gl_lds16(gb, Bs + (w * 2 + jj) * 512);
    }
    __syncthreads();
    short8 a[4], b[4];
#pragma unroll
    for (int i = 0; i < 4; i++)
      a[i] = *(const short8*)&As[(wm * 64 + i * 16 + (l & 15)) * 32 + (l >> 4) * 8];
#pragma unroll
    for (int j = 0; j < 4; j++)
      b[j] = *(const short8*)&Bs[(wn * 64 + j * 16 + (l & 15)) * 32 + (l >> 4) * 8];
#pragma unroll
    for (int i = 0; i < 4; i++)
#pragma unroll
      for (int j = 0; j < 4; j++)
        acc[i][j] = __builtin_amdgcn_mfma_f32_16x16x32_bf16(a[i], b[j], acc[i][j], 0, 0, 0);
  }
#pragma unroll
  for (int j = 0; j < 4; j++) {
    int cg = nt * 128 + wn * 64 + j * 16 + (l & 15);
    float bv = bias[cg];
#pragma unroll
    for (int i = 0; i < 4; i++) {
      int rbase = mt * 128 + wm * 64 + i * 16 + (l >> 4) * 4;
#pragma unroll
      for (int r = 0; r < 4; r++)
        Cout[(size_t)(rbase + r) * 2048 + cg] = acc[i][j][r] + bv;
    }
  }
}

// ---------------- LSTM recurrence core (templated on exchange scope) ----------------
template <bool L2>
__device__ __forceinline__ void lstm_core(
    int m, int s, int tid,
    const unsigned short* __restrict__ whh,
    const float* __restrict__ gxf,
    unsigned* __restrict__ hring,
    unsigned short (*Hs)[16][520], float (*Gt)[132]) {
  const int w = tid >> 6, l = tid & 63;

  // ---- preload W_hh fragments (constant over t) ----
  short8 bw[16][2];
#pragma unroll
  for (int u = 0; u < 2; u++) {
    int n = (2 * w + u) * 16 + (l & 15);
    int jn = n >> 2, g = n & 3;
    int R = g * 512 + s * 32 + jn;
    const unsigned short* base = whh + (size_t)R * 512 + ((l >> 4) * 8);
#pragma unroll
    for (int kk = 0; kk < 16; kk++) bw[kk][u] = *(const short8*)(base + kk * 32);
  }

  const int b = l & 15;
  const int p = 4 * w + (l >> 4);
  const int gb = m * 16 + b;
  const int colg = s * 32 + 2 * p;
  float c0 = 0.f, c1 = 0.f;

  unsigned* gring = hring + (size_t)m * GR_U;  // this group's ring
  const unsigned long long* gq = (const unsigned long long*)gring;

  const int skc = tid & 127;
  const int srow = tid >> 7;
  const bool selfst = ((skc >> 3) == s);

  // ---- initial loads for t=0 ----
  unsigned long long v[8];
#pragma unroll
  for (int it = 0; it < 8; it++)
    v[it] = ld8<L2>(&gq[(size_t)(it * 2 + srow) * 128 + skc]);
  float2 pg[4];
  {
    size_t base0 = (size_t)gb * G4 + colg;
#pragma unroll
    for (int g = 0; g < 4; g++) pg[g] = *(const float2*)(gxf + base0 + (size_t)g * 512);
  }

  for (int t = 0; t < S_LEN; t++) {
    const int buf = t & 1;
    const unsigned long long* src = gq + (size_t)t * SLOT_Q;

    // ---- finalize stripe: reload only sentinel lanes (skip self-stripe at t>0) ----
    if (!(selfst && t > 0)) {
      int spins = 0;
      for (;;) {
        int bad = 0;
#pragma unroll
        for (int it = 0; it < 8; it++)
          bad |= (((unsigned)v[it] == SENT) | ((unsigned)(v[it] >> 32) == SENT)) << it;
        if (!bad) break;
        ++spins;
        bool esc = L2 && ((spins & 63) == 0);  // progress guarantee escape
#pragma unroll
        for (int it = 0; it < 8; it++)
          if ((bad >> it) & 1) {
            const unsigned long long* q = &src[(size_t)(it * 2 + srow) * 128 + skc];
            v[it] = esc ? ld8_agent(q) : ld8<L2>(q);
          }
      }
#pragma unroll
      for (int it = 0; it < 8; it++)
        *(unsigned long long*)&Hs[buf][it * 2 + srow][skc * 4] = v[it];
    }
    __syncthreads();

    // ---- speculative prefetch for t+1 ----
    unsigned long long vn[8];
    float2 pgn[4];
    if (t + 1 < S_LEN) {
      if (!selfst) {
        const unsigned long long* srcn = gq + (size_t)(t + 1) * SLOT_Q;
#pragma unroll
        for (int it = 0; it < 8; it++)
          vn[it] = ld8<L2>(&srcn[(size_t)(it * 2 + srow) * 128 + skc]);
      }
      size_t basen = (size_t)((t + 1) * BATCH + gb) * G4 + colg;
#pragma unroll
      for (int g = 0; g < 4; g++) pgn[g] = *(const float2*)(gxf + basen + (size_t)g * 512);
    }

    // ---- gates tile via MFMA ----
    f32x4 acc0 = f32x4{0.f, 0.f, 0.f, 0.f};
    f32x4 acc1 = f32x4{0.f, 0.f, 0.f, 0.f};
#pragma unroll
    for (int kk = 0; kk < 16; kk++) {
      short8 a = *(const short8*)&Hs[buf][l & 15][kk * 32 + (l >> 4) * 8];
      acc0 = __builtin_amdgcn_mfma_f32_16x16x32_bf16(a, bw[kk][0], acc0, 0, 0, 0);
      acc1 = __builtin_amdgcn_mfma_f32_16x16x32_bf16(a, bw[kk][1], acc1, 0, 0, 0);
    }
#pragma unroll
    for (int r = 0; r < 4; r++) {
      Gt[(l >> 4) * 4 + r][(2 * w + 0) * 16 + (l & 15)] = acc0[r];
      Gt[(l >> 4) * 4 + r][(2 * w + 1) * 16 + (l & 15)] = acc1[r];
    }

    // ---- pointwise ----
    float4 g0 = *(const float4*)&Gt[b][8 * p];
    float4 g1 = *(const float4*)&Gt[b][8 * p + 4];
    float i0 = sigm(g0.x + pg[0].x), f0 = sigm(g0.y + pg[1].x);
    float gg0 = tanh_fast(g0.z + pg[2].x), o0 = sigm(g0.w + pg[3].x);
    c0 = f0 * c0 + i0 * gg0;
    float h0 = o0 * tanh_fast(c0);
    float i1 = sigm(g1.x + pg[0].y), f1 = sigm(g1.y + pg[1].y);
    float gg1 = tanh_fast(g1.z + pg[2].y), o1 = sigm(g1.w + pg[3].y);
    c1 = f1 * c1 + i1 * gg1;
    float h1 = o1 * tanh_fast(c1);
    unsigned hp = (unsigned)f32_bf16(h0) | ((unsigned)f32_bf16(h1) << 16);

    // ---- publish h(t+1): ring (write-once slot) + next Hs buffer (self cols) ----
    st4<L2>(&gring[(size_t)(t + 1) * SLOT_U + b * 256 + s * 16 + p], hp);
    *(unsigned*)&Hs[buf ^ 1][b][colg] = hp;

#pragma unroll
    for (int it = 0; it < 8; it++) v[it] = vn[it];
#pragma unroll
    for (int g = 0; g < 4; g++) pg[g] = pgn[g];
  }
}

// ---------------- persistent LSTM recurrence ----------------
// 256 blocks cooperative. Startup: read XCC_ID, register rank on own XCD.
// If every XCD got >=16 blocks: groups are XCD-LOCAL -> exchange via the
// shared per-XCD L2 (volatile sc0 loads / write-through stores), ~3x lower
// hop latency than LLC. Else: fall back to agent-scope protocol (placement-
// independent, R8-proven). Spin-escape keeps the L2 path deadlock-free.
__global__ __launch_bounds__(256, 1) void lstm_rec(
    const unsigned short* __restrict__ whh,
    const float* __restrict__ gx,
    unsigned* __restrict__ hring,
    unsigned* __restrict__ ctrl) {  // [0..7] xcd counts, [8] barrier
  __shared__ __align__(16) unsigned short Hs[2][16][520];
  __shared__ __align__(16) float Gt[16][132];
  __shared__ unsigned sh_xcd, sh_rank, sh_mode;

  const int tid = threadIdx.x;
  if (tid == 0) {
    unsigned x;
    asm("s_getreg_b32 %0, hwreg(HW_REG_XCC_ID)" : "=s"(x));
    x &= 7u;
    unsigned r = __hip_atomic_fetch_add(&ctrl[x], 1u, __ATOMIC_RELAXED,
                                        __HIP_MEMORY_SCOPE_AGENT);
    __hip_atomic_fetch_add(&ctrl[8], 1u, __ATOMIC_RELEASE, __HIP_MEMORY_SCOPE_AGENT);
    while (__hip_atomic_load(&ctrl[8], __ATOMIC_ACQUIRE, __HIP_MEMORY_SCOPE_AGENT) <
           gridDim.x) {}
    unsigned ok = 1;
#pragma unroll
    for (int g = 0; g < 8; g++)
      ok &= (__hip_atomic_load(&ctrl[g], __ATOMIC_RELAXED, __HIP_MEMORY_SCOPE_AGENT) >= 16u);
    sh_xcd = x; sh_rank = r; sh_mode = ok;
  }
  __syncthreads();

  if (sh_mode) {
    if (sh_rank < 16)
      lstm_core<true>((int)sh_xcd, (int)sh_rank, tid, whh, gx, hring, Hs, Gt);
  } else {
    if (blockIdx.x < 128)
      lstm_core<false>((int)(blockIdx.x & 7), (int)(blockIdx.x >> 3), tid, whh, gx, hring,
                       Hs, Gt);
  }
}

// ---------------- final reduction: sum over 8 groups' slot-256 ----------------
__global__ void reduce_sum(const unsigned* __restrict__ hring, float* __restrict__ out) {
  __shared__ float red[256];
  int tid = threadIdx.x;
  float s = 0.f;
  for (int g = 0; g < 8; g++) {
    const unsigned* base = hring + (size_t)g * GR_U + (size_t)256 * SLOT_U;
    for (int i = tid; i < SLOT_U; i += 256) {
      unsigned q = base[i];
      s += bf16_f32((unsigned short)(q & 0xFFFFu));
      s += bf16_f32((unsigned short)(q >> 16));
    }
  }
  red[tid] = s;
  __syncthreads();
  for (int off = 128; off > 0; off >>= 1) {
    if (tid < off) red[tid] += red[tid + off];
    __syncthreads();
  }
  if (tid == 0) out[0] = red[0];
}

// ---------------- launch ----------------
extern "C" void kernel_launch(void* const* d_in, const int* in_sizes, int n_in,
                              void* d_out, int out_size, void* d_ws, size_t ws_size,
                              hipStream_t stream) {
  const float* x = (const float*)d_in[0];     // [256][128][1024]
  const float* w_ih = (const float*)d_in[1];  // [2048][1024]
  const float* w_hh = (const float*)d_in[2];  // [2048][512]
  const float* b_ih = (const float*)d_in[3];  // [2048]
  const float* b_hh = (const float*)d_in[4];  // [2048]

  char* ws = (char*)d_ws;
  unsigned short* x_bf = (unsigned short*)(ws);                 // 67,108,864 B
  unsigned short* wih_bf = (unsigned short*)(ws + 67108864);    //  4,194,304 B
  unsigned short* whh_bf = (unsigned short*)(ws + 71303168);    //  2,097,152 B
  float* bias = (float*)(ws + 73400320);                        //      8,192 B
  unsigned* ctrl = (unsigned*)(ws + 73408512);                  //        256 B
  unsigned* hring = (unsigned*)(ws + 73408768);                 // 33,685,504 B
  float* gx = (float*)(ws + 107094272);                         // 268,435,456 B

  // conversions + init
  cvt_bf16<<<(33554432 / 4 + 255) / 256, 256, 0, stream>>>(x, x_bf, 33554432);
  cvt_bf16<<<(2097152 / 4 + 255) / 256, 256, 0, stream>>>(w_ih, wih_bf, 2097152);
  cvt_bf16<<<(1048576 / 4 + 255) / 256, 256, 0, stream>>>(w_hh, whh_bf, 1048576);
  init_all<<<256, 256, 0, stream>>>(b_ih, b_hh, bias, ctrl, (uint4*)hring);

  // big input GEMM (bias folded)
  gemm_bias<<<4096, 256, 0, stream>>>(x_bf, wih_bf, bias, gx);

  // persistent recurrence: 256 blocks, XCD-local groups when possible
  void* args[] = {(void*)&whh_bf, (void*)&gx, (void*)&hring, (void*)&ctrl};
  hipLaunchCooperativeKernel((const void*)lstm_rec, dim3(256), dim3(256), args, 0, stream);

  // scalar output
  reduce_sum<<<1, 256, 0, stream>>>(hring, (float*)d_out);
}